// Round 2
// baseline (223.167 us; speedup 1.0000x reference)
//
#include <hip/hip_runtime.h>
#include <hip/hip_bf16.h>

// N,C,K,P,Q,PS = 32,128,128,64,64,3
#define NN 32
#define CCH 128
#define KK 128
#define PP 64
#define QQ 64

typedef __bf16 bf16x8 __attribute__((ext_vector_type(8)));
typedef float f32x16 __attribute__((ext_vector_type(16)));
typedef float f32x4 __attribute__((ext_vector_type(4)));

// Workspace:
//   xT: [N][8 cc][P][Q][16 c] bf16 = 33,554,432 B   (c-chunk-major!)
//   Wf: [8 cc][9 t][4 kb][64 lane][8 bf16] = 294,912 B
#define XT_ELEMS (32ull * 64 * 64 * 128)

// ---------- prep 1: x (NCHW f32) -> xT ([n][cc][p][q][16c] bf16) ----------
// (unchanged — verified)
__global__ __launch_bounds__(256) void prep_x(const float* __restrict__ x,
                                              __bf16* __restrict__ xT) {
    __shared__ float tile[128 * 64];
    const int t = threadIdx.x;
    const int p = blockIdx.x;
    const int n = blockIdx.y;

#pragma unroll
    for (int pass = 0; pass < 8; ++pass) {
        int idx = pass * 256 + t;
        int qf = idx & 15;
        int c  = idx >> 4;
        f32x4 v = *(const f32x4*)(x + (((size_t)n * CCH + c) * PP + p) * QQ + qf * 4);
        int key = ((c >> 3) & 15) * 4;
        *(f32x4*)(tile + c * 64 + ((qf * 4) ^ key)) = v;
    }
    __syncthreads();

#pragma unroll
    for (int pass = 0; pass < 4; ++pass) {
        int cc   = pass * 2 + (t >> 7);
        int rem  = t & 127;
        int q    = rem >> 1;
        int half = rem & 1;
        int c0   = cc * 16 + half * 8;
        int key  = ((c0 >> 3) & 15) * 4;
        bf16x8 o;
#pragma unroll
        for (int j = 0; j < 8; ++j) o[j] = (__bf16)tile[(c0 + j) * 64 + (q ^ key)];
        *(bf16x8*)(xT + ((((size_t)n * 8 + cc) * PP + p) * QQ + q) * 16 + half * 8) = o;
    }
}

// ---------- prep 2: W -> Wf fragment order (unchanged — verified) ----------
__global__ __launch_bounds__(256) void prep_w(const float* __restrict__ W,
                                              __bf16* __restrict__ Wf) {
    const int id = blockIdx.x * 256 + threadIdx.x;  // 18432
    const int lane = id & 63;
    const int r1   = id >> 6;
    const int kb   = r1 & 3;
    const int r2   = r1 >> 2;
    const int t    = r2 % 9;
    const int cc   = r2 / 9;

    const int k  = kb * 32 + (lane & 31);
    const int c0 = cc * 16 + (lane >> 5) * 8;

    bf16x8 o;
#pragma unroll
    for (int j = 0; j < 8; ++j)
        o[j] = (__bf16)W[(size_t)k * (CCH * 9) + (size_t)(c0 + j) * 9 + t];
    ((bf16x8*)Wf)[id] = o;
}

// ---------- main: implicit GEMM conv ----------
// Block: 8 p-rows x 64 q x 128 k, 512 threads (8 waves); 1 block/CU.
// cc loop: dbuf + 1 barrier/cc (round-1 structure, measured ~16 us — fine).
// NEW (round 2): the epilogue was the real bottleneck (~50 us of scalar 4B
// per-loads + out-stores). Fix:
//   (a) peel cc=7; issue ALL per loads as f32x4 into regs BEFORE its compute
//       (addresses are index-only; ~4600 cyc of MFMA covers ~700 cyc latency)
//   (b) epilogue: per-wave 4 KB XOR-swizzled LDS transpose of each 32x32 acc
//       tile -> f32x4 ds_read -> add prefetched per -> f32x4 store
//       (8 x 128 B segments per store instr, 4x fewer VMEM instructions).
// No barrier before epilogue: cc=7 reads only wlds[1]/xlds[1]; scratch=wlds[0].
#define XPITCH 2112  // bytes per padded x row in LDS (66 * 32)
#define WBYTES 36864
#define XROWS  10
#define XBYTES (XROWS * XPITCH)  // 21,120

__global__ __launch_bounds__(512, 2) void conv_main(const __bf16* __restrict__ xT,
                                                    const __bf16* __restrict__ Wf,
                                                    const float* __restrict__ per,
                                                    float* __restrict__ out) {
    __shared__ __align__(16) char wlds[2][WBYTES];
    __shared__ __align__(16) char xlds[2][XBYTES];

    const int tid  = threadIdx.x;
    const int lane = tid & 63;
    const int w    = tid >> 6;   // 0..7
    const int kbs  = w & 1;
    const int pb   = w >> 1;     // 0..3
    const int n    = blockIdx.y;
    const int p0   = blockIdx.x * 8;
    const int m    = lane & 31;
    const int half = lane >> 5;

    // zero the pad columns (q=-1 and q=64 slots) in BOTH buffers, once
    if (tid < 40) {
        int row = tid >> 2, part = tid & 3;
        int off = row * XPITCH + (part >> 1) * 2080 + (part & 1) * 16;
        *(f32x4*)(xlds[0] + off) = f32x4{0.f, 0.f, 0.f, 0.f};
        *(f32x4*)(xlds[1] + off) = f32x4{0.f, 0.f, 0.f, 0.f};
    }

    f32x16 acc[2][2][2];  // [oi][kb][qb]
#pragma unroll
    for (int a = 0; a < 2; ++a)
#pragma unroll
        for (int b = 0; b < 2; ++b)
#pragma unroll
            for (int c = 0; c < 2; ++c)
#pragma unroll
                for (int e = 0; e < 16; ++e) acc[a][b][c][e] = 0.f;

    const char* xb = (const char*)xT + ((size_t)n * 8) * PP * QQ * 32;  // + cc*PP*QQ*32

    auto stage = [&](int ccn, int buf) {
        const char* g = (const char*)Wf + (size_t)ccn * WBYTES;
#pragma unroll
        for (int it = 0; it < 5; ++it) {
            int idx = it * 512 + tid;
            if (idx < WBYTES / 16) {
                __builtin_amdgcn_global_load_lds(
                    (const __attribute__((address_space(1))) unsigned int*)(g + idx * 16),
                    (__attribute__((address_space(3))) unsigned int*)(wlds[buf] + idx * 16),
                    16, 0, 0);
            }
        }
        const char* gx = xb + (size_t)ccn * (PP * QQ * 32);
#pragma unroll
        for (int it = 0; it < 3; ++it) {
            int gi = it * 512 + tid;
            if (gi < XROWS * 128) {
                int row = gi >> 7;              // wave-uniform (64 | 128)
                int wi  = (gi & 127) * 16;
                int r   = p0 - 1 + row;
                int rc  = r < 0 ? 0 : (r > 63 ? 63 : r);
                __builtin_amdgcn_global_load_lds(
                    (const __attribute__((address_space(1))) unsigned int*)(gx + (size_t)rc * 2048 + wi),
                    (__attribute__((address_space(3))) unsigned int*)(xlds[buf] + row * XPITCH + 32 + wi),
                    16, 0, 0);
            }
        }
    };

    // one cc-step of compute on buffer `buf` (shared by loop + peeled last iter)
    auto compute = [&](int buf) {
        const char* wbase = wlds[buf];
        const char* xbase = xlds[buf];

        bf16x8 a_cur[3][2], a_prev[3][2];
#pragma unroll
        for (int ri = 0; ri < 4; ++ri) {
            const int rr = pb * 2 + ri;            // xlds row 0..9
            const int r  = p0 + pb * 2 + ri - 1;   // global input row
            const bool rok = ((unsigned)r < (unsigned)PP);  // wave-uniform

            bf16x8 b[3][2];
            if (rok) {
                const char* rbase = xbase + rr * XPITCH + half * 16;
#pragma unroll
                for (int dq = 0; dq < 3; ++dq)
#pragma unroll
                    for (int qb = 0; qb < 2; ++qb)
                        b[dq][qb] = *(const bf16x8*)(rbase + (qb * 32 + m + dq) * 32);
            }

            if (ri < 3) {
#pragma unroll
                for (int dq = 0; dq < 3; ++dq)
#pragma unroll
                    for (int kb = 0; kb < 2; ++kb)
                        a_cur[dq][kb] = ((const bf16x8*)wbase)[((ri * 3 + dq) * 4 +
                                                                kbs * 2 + kb) * 64 + lane];
            }

            if (rok) {
                if (ri >= 1) {
#pragma unroll
                    for (int dq = 0; dq < 3; ++dq)
#pragma unroll
                        for (int kb = 0; kb < 2; ++kb)
#pragma unroll
                            for (int qb = 0; qb < 2; ++qb)
                                acc[1][kb][qb] = __builtin_amdgcn_mfma_f32_32x32x16_bf16(
                                    a_prev[dq][kb], b[dq][qb], acc[1][kb][qb], 0, 0, 0);
                }
                if (ri < 3) {
#pragma unroll
                    for (int dq = 0; dq < 3; ++dq)
#pragma unroll
                        for (int kb = 0; kb < 2; ++kb)
#pragma unroll
                            for (int qb = 0; qb < 2; ++qb)
                                acc[0][kb][qb] = __builtin_amdgcn_mfma_f32_32x32x16_bf16(
                                    a_cur[dq][kb], b[dq][qb], acc[0][kb][qb], 0, 0, 0);
                }
            }

            if (ri < 3) {
#pragma unroll
                for (int dq = 0; dq < 3; ++dq)
#pragma unroll
                    for (int kb = 0; kb < 2; ++kb) a_prev[dq][kb] = a_cur[dq][kb];
            }
        }
    };

    stage(0, 0);
    __syncthreads();  // prologue: only exposed staging wait

    for (int cc = 0; cc < 7; ++cc) {
        stage(cc + 1, (cc + 1) & 1);  // issue BEFORE compute -> overlap
        compute(cc & 1);
        __syncthreads();              // drains stage(cc+1); buf cc&1 now free
    }

    // ---- peeled cc=7: prefetch ALL per values (f32x4) under the last compute ----
    // pv[oi][kbi][qb][j] matches the POST-transpose element mapping below:
    //   k_local = (lane>>3) + j*8, q_local = (lane&7)*4 .. +3
    f32x4 pv[2][2][2][4];
#pragma unroll
    for (int oi = 0; oi < 2; ++oi) {
        const int prow = p0 + pb * 2 + oi;
#pragma unroll
        for (int kbi = 0; kbi < 2; ++kbi) {
#pragma unroll
            for (int qb = 0; qb < 2; ++qb) {
#pragma unroll
                for (int j = 0; j < 4; ++j) {
                    int k = (kbs * 2 + kbi) * 32 + (lane >> 3) + j * 8;
                    int q = qb * 32 + (lane & 7) * 4;
                    pv[oi][kbi][qb][j] =
                        *(const f32x4*)(per + (((size_t)n * KK + k) * PP + prow) * QQ + q);
                }
            }
        }
    }

    compute(1);  // cc=7 uses buffer 1 (reads wlds[1]/xlds[1] only)

    // ---- epilogue: per-wave XOR-swizzled LDS transpose, all f32x4 traffic ----
    // scratch = wlds[0] (dead: cc=7 read buffer 1); 8 waves x 4 KB = 32 KB.
    // write: element (k_local, q=m): f32 at k_local*32 + ((q>>2)^(k_local&7))*4 + (q&3)
    //   -> fixed r: 64 lanes hit each bank exactly twice (free).
    // read: lane l, pass j: k_local=(l>>3)+j*8, 16B at col ((l&7)^(k_local&7))
    //   -> (l&7)^(l>>3) bijective per 8-lane group: conflict-minimal.
    float* scr = (float*)(wlds[0] + w * 4096);
#pragma unroll
    for (int oi = 0; oi < 2; ++oi) {
        const int prow = p0 + pb * 2 + oi;
#pragma unroll
        for (int kbi = 0; kbi < 2; ++kbi) {
#pragma unroll
            for (int qb = 0; qb < 2; ++qb) {
                f32x16 v = acc[oi][kbi][qb];
#pragma unroll
                for (int r = 0; r < 16; ++r) {
                    int kl = (r & 3) + 8 * (r >> 2) + 4 * half;
                    scr[kl * 32 + ((((m >> 2) ^ (kl & 7)) << 2) | (m & 3))] = v[r];
                }
                // same-wave LDS RAW: compiler inserts lgkmcnt wait (no barrier needed)
#pragma unroll
                for (int j = 0; j < 4; ++j) {
                    int kl = (lane >> 3) + j * 8;
                    f32x4 d = *(const f32x4*)(scr + kl * 32 + (((lane & 7) ^ (kl & 7)) << 2));
                    f32x4 s = d + pv[oi][kbi][qb][j];
                    int k = (kbs * 2 + kbi) * 32 + kl;
                    int q = qb * 32 + (lane & 7) * 4;
                    *(f32x4*)(out + (((size_t)n * KK + k) * PP + prow) * QQ + q) = s;
                }
            }
        }
    }
}

extern "C" void kernel_launch(void* const* d_in, const int* in_sizes, int n_in,
                              void* d_out, int out_size, void* d_ws, size_t ws_size,
                              hipStream_t stream) {
    const float* x   = (const float*)d_in[0];  // [32][128][64][64]
    const float* W   = (const float*)d_in[1];  // [128][1152]
    const float* per = (const float*)d_in[2];  // [32][128][64][64]
    float* out = (float*)d_out;

    __bf16* xT = (__bf16*)d_ws;
    __bf16* Wf = (__bf16*)((char*)d_ws + XT_ELEMS * 2);

    prep_x<<<dim3(PP, NN), 256, 0, stream>>>(x, xT);
    prep_w<<<dim3(72), 256, 0, stream>>>(W, Wf);
    conv_main<<<dim3(PP / 8, NN), 512, 0, stream>>>(xT, Wf, per, out);
}

// Round 3
// 211.458 us; speedup vs baseline: 1.0554x; 1.0554x over previous
//
#include <hip/hip_runtime.h>
#include <hip/hip_bf16.h>

// N,C,K,P,Q,PS = 32,128,128,64,64,3
#define NN 32
#define CCH 128
#define KK 128
#define PP 64
#define QQ 64

typedef __bf16 bf16x8 __attribute__((ext_vector_type(8)));
typedef float f32x16 __attribute__((ext_vector_type(16)));
typedef float f32x4 __attribute__((ext_vector_type(4)));

// Workspace:
//   xT: [N][8 cc][P][Q][16 c] bf16 = 33,554,432 B   (c-chunk-major!)
//   Wf: [8 cc][9 t][4 kb][64 lane][8 bf16] = 294,912 B
#define XT_ELEMS (32ull * 64 * 64 * 128)

// ---------- prep 1: x (NCHW f32) -> xT ([n][cc][p][q][16c] bf16) ----------
// (unchanged — verified)
__global__ __launch_bounds__(256) void prep_x(const float* __restrict__ x,
                                              __bf16* __restrict__ xT) {
    __shared__ float tile[128 * 64];
    const int t = threadIdx.x;
    const int p = blockIdx.x;
    const int n = blockIdx.y;

#pragma unroll
    for (int pass = 0; pass < 8; ++pass) {
        int idx = pass * 256 + t;
        int qf = idx & 15;
        int c  = idx >> 4;
        f32x4 v = *(const f32x4*)(x + (((size_t)n * CCH + c) * PP + p) * QQ + qf * 4);
        int key = ((c >> 3) & 15) * 4;
        *(f32x4*)(tile + c * 64 + ((qf * 4) ^ key)) = v;
    }
    __syncthreads();

#pragma unroll
    for (int pass = 0; pass < 4; ++pass) {
        int cc   = pass * 2 + (t >> 7);
        int rem  = t & 127;
        int q    = rem >> 1;
        int half = rem & 1;
        int c0   = cc * 16 + half * 8;
        int key  = ((c0 >> 3) & 15) * 4;
        bf16x8 o;
#pragma unroll
        for (int j = 0; j < 8; ++j) o[j] = (__bf16)tile[(c0 + j) * 64 + (q ^ key)];
        *(bf16x8*)(xT + ((((size_t)n * 8 + cc) * PP + p) * QQ + q) * 16 + half * 8) = o;
    }
}

// ---------- prep 2: W -> Wf fragment order (unchanged — verified) ----------
__global__ __launch_bounds__(256) void prep_w(const float* __restrict__ W,
                                              __bf16* __restrict__ Wf) {
    const int id = blockIdx.x * 256 + threadIdx.x;  // 18432
    const int lane = id & 63;
    const int r1   = id >> 6;
    const int kb   = r1 & 3;
    const int r2   = r1 >> 2;
    const int t    = r2 % 9;
    const int cc   = r2 / 9;

    const int k  = kb * 32 + (lane & 31);
    const int c0 = cc * 16 + (lane >> 5) * 8;

    bf16x8 o;
#pragma unroll
    for (int j = 0; j < 8; ++j)
        o[j] = (__bf16)W[(size_t)k * (CCH * 9) + (size_t)(c0 + j) * 9 + t];
    ((bf16x8*)Wf)[id] = o;
}

// ---------- main: implicit GEMM conv ----------
// Block: 8 p-rows x 64 q x 128 k, 512 threads (8 waves); 1 block/CU.
// cc loop: dbuf + 1 barrier/cc.
// Epilogue (round 3): LDS-transpose + f32x4 traffic, with DEPTH-1 per-prefetch.
// Round 2's bulk prefetch (pv[2][2][2][4] = 128 VGPR) blew the 256-reg cap ->
// scratch spill (WRITE_SIZE 65.5->108.5 MB, +10 us). Now: two named 4-vector
// buffers (32 VGPR), statically indexed after full unroll (rule #20); tile 0
// loads covered by the peeled cc=7 compute, tile i+1 loads covered by tile i's
// transpose+store work + 8-wave TLP.
#define XPITCH 2112  // bytes per padded x row in LDS (66 * 32)
#define WBYTES 36864
#define XROWS  10
#define XBYTES (XROWS * XPITCH)  // 21,120

__global__ __launch_bounds__(512, 2) void conv_main(const __bf16* __restrict__ xT,
                                                    const __bf16* __restrict__ Wf,
                                                    const float* __restrict__ per,
                                                    float* __restrict__ out) {
    __shared__ __align__(16) char wlds[2][WBYTES];
    __shared__ __align__(16) char xlds[2][XBYTES];

    const int tid  = threadIdx.x;
    const int lane = tid & 63;
    const int w    = tid >> 6;   // 0..7
    const int kbs  = w & 1;
    const int pb   = w >> 1;     // 0..3
    const int n    = blockIdx.y;
    const int p0   = blockIdx.x * 8;
    const int m    = lane & 31;
    const int half = lane >> 5;

    // zero the pad columns (q=-1 and q=64 slots) in BOTH buffers, once
    if (tid < 40) {
        int row = tid >> 2, part = tid & 3;
        int off = row * XPITCH + (part >> 1) * 2080 + (part & 1) * 16;
        *(f32x4*)(xlds[0] + off) = f32x4{0.f, 0.f, 0.f, 0.f};
        *(f32x4*)(xlds[1] + off) = f32x4{0.f, 0.f, 0.f, 0.f};
    }

    f32x16 acc[2][2][2];  // [oi][kb][qb]
#pragma unroll
    for (int a = 0; a < 2; ++a)
#pragma unroll
        for (int b = 0; b < 2; ++b)
#pragma unroll
            for (int c = 0; c < 2; ++c)
#pragma unroll
                for (int e = 0; e < 16; ++e) acc[a][b][c][e] = 0.f;

    const char* xb = (const char*)xT + ((size_t)n * 8) * PP * QQ * 32;  // + cc*PP*QQ*32

    auto stage = [&](int ccn, int buf) {
        const char* g = (const char*)Wf + (size_t)ccn * WBYTES;
#pragma unroll
        for (int it = 0; it < 5; ++it) {
            int idx = it * 512 + tid;
            if (idx < WBYTES / 16) {
                __builtin_amdgcn_global_load_lds(
                    (const __attribute__((address_space(1))) unsigned int*)(g + idx * 16),
                    (__attribute__((address_space(3))) unsigned int*)(wlds[buf] + idx * 16),
                    16, 0, 0);
            }
        }
        const char* gx = xb + (size_t)ccn * (PP * QQ * 32);
#pragma unroll
        for (int it = 0; it < 3; ++it) {
            int gi = it * 512 + tid;
            if (gi < XROWS * 128) {
                int row = gi >> 7;              // wave-uniform (64 | 128)
                int wi  = (gi & 127) * 16;
                int r   = p0 - 1 + row;
                int rc  = r < 0 ? 0 : (r > 63 ? 63 : r);
                __builtin_amdgcn_global_load_lds(
                    (const __attribute__((address_space(1))) unsigned int*)(gx + (size_t)rc * 2048 + wi),
                    (__attribute__((address_space(3))) unsigned int*)(xlds[buf] + row * XPITCH + 32 + wi),
                    16, 0, 0);
            }
        }
    };

    // one cc-step of compute on buffer `buf`
    auto compute = [&](int buf) {
        const char* wbase = wlds[buf];
        const char* xbase = xlds[buf];

        bf16x8 a_cur[3][2], a_prev[3][2];
#pragma unroll
        for (int ri = 0; ri < 4; ++ri) {
            const int rr = pb * 2 + ri;            // xlds row 0..9
            const int r  = p0 + pb * 2 + ri - 1;   // global input row
            const bool rok = ((unsigned)r < (unsigned)PP);  // wave-uniform

            bf16x8 b[3][2];
            if (rok) {
                const char* rbase = xbase + rr * XPITCH + half * 16;
#pragma unroll
                for (int dq = 0; dq < 3; ++dq)
#pragma unroll
                    for (int qb = 0; qb < 2; ++qb)
                        b[dq][qb] = *(const bf16x8*)(rbase + (qb * 32 + m + dq) * 32);
            }

            if (ri < 3) {
#pragma unroll
                for (int dq = 0; dq < 3; ++dq)
#pragma unroll
                    for (int kb = 0; kb < 2; ++kb)
                        a_cur[dq][kb] = ((const bf16x8*)wbase)[((ri * 3 + dq) * 4 +
                                                                kbs * 2 + kb) * 64 + lane];
            }

            if (rok) {
                if (ri >= 1) {
#pragma unroll
                    for (int dq = 0; dq < 3; ++dq)
#pragma unroll
                        for (int kb = 0; kb < 2; ++kb)
#pragma unroll
                            for (int qb = 0; qb < 2; ++qb)
                                acc[1][kb][qb] = __builtin_amdgcn_mfma_f32_32x32x16_bf16(
                                    a_prev[dq][kb], b[dq][qb], acc[1][kb][qb], 0, 0, 0);
                }
                if (ri < 3) {
#pragma unroll
                    for (int dq = 0; dq < 3; ++dq)
#pragma unroll
                        for (int kb = 0; kb < 2; ++kb)
#pragma unroll
                            for (int qb = 0; qb < 2; ++qb)
                                acc[0][kb][qb] = __builtin_amdgcn_mfma_f32_32x32x16_bf16(
                                    a_cur[dq][kb], b[dq][qb], acc[0][kb][qb], 0, 0, 0);
                }
            }

            if (ri < 3) {
#pragma unroll
                for (int dq = 0; dq < 3; ++dq)
#pragma unroll
                    for (int kb = 0; kb < 2; ++kb) a_prev[dq][kb] = a_cur[dq][kb];
            }
        }
    };

    stage(0, 0);
    __syncthreads();  // prologue: only exposed staging wait

    for (int cc = 0; cc < 7; ++cc) {
        stage(cc + 1, (cc + 1) & 1);  // issue BEFORE compute -> overlap
        compute(cc & 1);
        __syncthreads();              // drains stage(cc+1); buf cc&1 now free
    }

    // ---- epilogue helpers ----
    // tile it = 0..7: oi = it>>2, kbi = (it>>1)&1, qb = it&1.
    // per/out address for lane, pass j (post-transpose mapping):
    //   k = (kbs*2+kbi)*32 + (lane>>3) + j*8, q = qb*32 + (lane&7)*4
    auto tile_addr = [&](int it, int j) -> size_t {
        int oi = it >> 2, kbi = (it >> 1) & 1, qb = it & 1;
        int prow = p0 + pb * 2 + oi;
        int k = (kbs * 2 + kbi) * 32 + (lane >> 3) + j * 8;
        int q = qb * 32 + (lane & 7) * 4;
        return (((size_t)n * KK + k) * PP + prow) * QQ + q;
    };

    float* scr = (float*)(wlds[0] + w * 4096);  // per-wave 4 KB scratch (dead buf 0)

    // transpose acc tile `it` through LDS (XOR-swizzled, conflict-free),
    // add per values from pv, store f32x4 nontemporal.
    auto process = [&](int it, f32x4 (&pv)[4]) {
        int oi = it >> 2, kbi = (it >> 1) & 1, qb = it & 1;
        f32x16 v = acc[oi][kbi][qb];
#pragma unroll
        for (int r = 0; r < 16; ++r) {
            int kl = (r & 3) + 8 * (r >> 2) + 4 * half;
            scr[kl * 32 + ((((m >> 2) ^ (kl & 7)) << 2) | (m & 3))] = v[r];
        }
        // same-wave LDS RAW: compiler inserts lgkmcnt wait
#pragma unroll
        for (int j = 0; j < 4; ++j) {
            int kl = (lane >> 3) + j * 8;
            f32x4 d = *(const f32x4*)(scr + kl * 32 + (((lane & 7) ^ (kl & 7)) << 2));
            f32x4 s = d + pv[j];
            __builtin_nontemporal_store(s, (f32x4*)(out + tile_addr(it, j)));
        }
    };

    // ---- peeled cc=7 with depth-1 per prefetch (32 VGPR total, no spill) ----
    f32x4 pv0[4], pv1[4];
#pragma unroll
    for (int j = 0; j < 4; ++j) pv0[j] = *(const f32x4*)(per + tile_addr(0, j));

    compute(1);  // cc=7 uses buffer 1 (reads wlds[1]/xlds[1] only)

#pragma unroll
    for (int itp = 0; itp < 4; ++itp) {
        const int itA = itp * 2, itB = itp * 2 + 1;
        // prefetch tile itB while pv0 holds itA
#pragma unroll
        for (int j = 0; j < 4; ++j) pv1[j] = *(const f32x4*)(per + tile_addr(itB, j));
        process(itA, pv0);
        if (itp < 3) {
#pragma unroll
            for (int j = 0; j < 4; ++j)
                pv0[j] = *(const f32x4*)(per + tile_addr(itA + 2, j));
        }
        process(itB, pv1);
    }
}

extern "C" void kernel_launch(void* const* d_in, const int* in_sizes, int n_in,
                              void* d_out, int out_size, void* d_ws, size_t ws_size,
                              hipStream_t stream) {
    const float* x   = (const float*)d_in[0];  // [32][128][64][64]
    const float* W   = (const float*)d_in[1];  // [128][1152]
    const float* per = (const float*)d_in[2];  // [32][128][64][64]
    float* out = (float*)d_out;

    __bf16* xT = (__bf16*)d_ws;
    __bf16* Wf = (__bf16*)((char*)d_ws + XT_ELEMS * 2);

    prep_x<<<dim3(PP, NN), 256, 0, stream>>>(x, xT);
    prep_w<<<dim3(72), 256, 0, stream>>>(W, Wf);
    conv_main<<<dim3(PP / 8, NN), 512, 0, stream>>>(xT, Wf, per, out);
}

// Round 4
// 209.591 us; speedup vs baseline: 1.0648x; 1.0089x over previous
//
#include <hip/hip_runtime.h>
#include <hip/hip_bf16.h>

// N,C,K,P,Q,PS = 32,128,128,64,64,3
#define NN 32
#define CCH 128
#define KK 128
#define PP 64
#define QQ 64

typedef __bf16 bf16x8 __attribute__((ext_vector_type(8)));
typedef float f32x16 __attribute__((ext_vector_type(16)));
typedef float f32x4 __attribute__((ext_vector_type(4)));

// Workspace:
//   xT: [N][8 cc][P][Q][16 c] bf16 = 33,554,432 B   (c-chunk-major!)
//   Wf: [8 cc][9 t][4 kb][64 lane][8 bf16] = 294,912 B
#define XT_ELEMS (32ull * 64 * 64 * 128)

// ---------- prep 1: x (NCHW f32) -> xT ([n][cc][p][q][16c] bf16) ----------
// (unchanged — verified)
__global__ __launch_bounds__(256) void prep_x(const float* __restrict__ x,
                                              __bf16* __restrict__ xT) {
    __shared__ float tile[128 * 64];
    const int t = threadIdx.x;
    const int p = blockIdx.x;
    const int n = blockIdx.y;

#pragma unroll
    for (int pass = 0; pass < 8; ++pass) {
        int idx = pass * 256 + t;
        int qf = idx & 15;
        int c  = idx >> 4;
        f32x4 v = *(const f32x4*)(x + (((size_t)n * CCH + c) * PP + p) * QQ + qf * 4);
        int key = ((c >> 3) & 15) * 4;
        *(f32x4*)(tile + c * 64 + ((qf * 4) ^ key)) = v;
    }
    __syncthreads();

#pragma unroll
    for (int pass = 0; pass < 4; ++pass) {
        int cc   = pass * 2 + (t >> 7);
        int rem  = t & 127;
        int q    = rem >> 1;
        int half = rem & 1;
        int c0   = cc * 16 + half * 8;
        int key  = ((c0 >> 3) & 15) * 4;
        bf16x8 o;
#pragma unroll
        for (int j = 0; j < 8; ++j) o[j] = (__bf16)tile[(c0 + j) * 64 + (q ^ key)];
        *(bf16x8*)(xT + ((((size_t)n * 8 + cc) * PP + p) * QQ + q) * 16 + half * 8) = o;
    }
}

// ---------- prep 2: W -> Wf fragment order (unchanged — verified) ----------
__global__ __launch_bounds__(256) void prep_w(const float* __restrict__ W,
                                              __bf16* __restrict__ Wf) {
    const int id = blockIdx.x * 256 + threadIdx.x;  // 18432
    const int lane = id & 63;
    const int r1   = id >> 6;
    const int kb   = r1 & 3;
    const int r2   = r1 >> 2;
    const int t    = r2 % 9;
    const int cc   = r2 / 9;

    const int k  = kb * 32 + (lane & 31);
    const int c0 = cc * 16 + (lane >> 5) * 8;

    bf16x8 o;
#pragma unroll
    for (int j = 0; j < 8; ++j)
        o[j] = (__bf16)W[(size_t)k * (CCH * 9) + (size_t)(c0 + j) * 9 + t];
    ((bf16x8*)Wf)[id] = o;
}

// ---------- main: implicit GEMM conv, W from L2 (round 4) ----------
// Evidence (R0=69, R1=72, R3=72 us regardless of sync/epilogue structure):
// latency-bound at 2 waves/SIMD (reg-capped: 128 AGPR acc + ~116 VGPR).
// This round: A-operand (W) loaded STRAIGHT from global into the existing
// a_cur/a_prev registers. Wf = 288 KB = permanently L2-resident per XCD, so
// these are ~200-cyc L2 hits, pipelined by the ri-rotation. Removes:
//   - W global_load_lds staging (and its share of the barrier's vmcnt drain)
//   - 18 ds_read_b128/wave/cc of LDS-port pressure (1152 cyc/cc/CU)
// LDS now: x dbuf (25,344 B) + 16 KB epilogue scratch = 41,728 B.
// Block shrinks to 4 p-rows / 256 thr / 4 waves; grid 16x32 = 512 blocks ->
// 2 independent blocks/CU (same 8 waves/CU, but phase-decoupled: one block's
// epilogue VMEM overlaps the other's MFMA/LDS — the R0 jitter win, kept).
#define XPITCH 2112  // bytes per padded x row in LDS (66 * 32)
#define XROWS  6
#define XBYTES (XROWS * XPITCH)  // 12,672

__global__ __launch_bounds__(256, 2) void conv_main(const __bf16* __restrict__ xT,
                                                    const __bf16* __restrict__ Wf,
                                                    const float* __restrict__ per,
                                                    float* __restrict__ out) {
    __shared__ __align__(16) char xlds[2][XBYTES];     // 25,344
    __shared__ __align__(16) char scr_lds[4][4096];    // per-wave epilogue scratch

    const int tid  = threadIdx.x;
    const int lane = tid & 63;
    const int w    = tid >> 6;   // 0..3
    const int kbs  = w & 1;
    const int pb   = w >> 1;     // 0..1
    const int n    = blockIdx.y;
    const int p0   = blockIdx.x * 4;
    const int m    = lane & 31;
    const int half = lane >> 5;

    // zero the pad columns (q=-1 and q=64 slots) in BOTH buffers, once
    if (tid < 24) {
        int row = tid >> 2, part = tid & 3;
        int off = row * XPITCH + (part >> 1) * 2080 + (part & 1) * 16;
        *(f32x4*)(xlds[0] + off) = f32x4{0.f, 0.f, 0.f, 0.f};
        *(f32x4*)(xlds[1] + off) = f32x4{0.f, 0.f, 0.f, 0.f};
    }

    f32x16 acc[2][2][2];  // [oi][kb][qb]
#pragma unroll
    for (int a = 0; a < 2; ++a)
#pragma unroll
        for (int b = 0; b < 2; ++b)
#pragma unroll
            for (int c = 0; c < 2; ++c)
#pragma unroll
                for (int e = 0; e < 16; ++e) acc[a][b][c][e] = 0.f;

    const char* xb = (const char*)xT + ((size_t)n * 8) * PP * QQ * 32;  // + cc*PP*QQ*32

    // W fragment base for this wave: frag id = cc*2304 + (t*4 + kbs*2 + kb)*64 + lane
    const bf16x8* wg = (const bf16x8*)Wf + kbs * 128 + lane;

    // stage x rows p0-1 .. p0+4 for chunk ccn: 768 lane-ops = exactly 3 passes
    auto stage_x = [&](int ccn, int buf) {
        const char* gx = xb + (size_t)ccn * (PP * QQ * 32);
#pragma unroll
        for (int it = 0; it < 3; ++it) {
            int gi  = it * 256 + tid;       // 0..767; 128 chunks/row
            int row = gi >> 7;              // wave-uniform
            int wi  = (gi & 127) * 16;
            int r   = p0 - 1 + row;
            int rc  = r < 0 ? 0 : (r > 63 ? 63 : r);
            __builtin_amdgcn_global_load_lds(
                (const __attribute__((address_space(1))) unsigned int*)(gx + (size_t)rc * 2048 + wi),
                (__attribute__((address_space(3))) unsigned int*)(xlds[buf] + row * XPITCH + 32 + wi),
                16, 0, 0);
        }
    };

    // one cc-step; A-frags come from global (L2-hot), x from xlds[buf]
    auto compute = [&](int buf, int cc) {
        const char* xbase = xlds[buf];
        const bf16x8* wc = wg + (size_t)cc * 2304;

        bf16x8 a_cur[3][2], a_prev[3][2];
#pragma unroll
        for (int ri = 0; ri < 4; ++ri) {
            const int rr = pb * 2 + ri;            // xlds row 0..5
            const int r  = p0 + pb * 2 + ri - 1;   // global input row
            const bool rok = ((unsigned)r < (unsigned)PP);  // wave-uniform

            bf16x8 b[3][2];
            if (rok) {
                const char* rbase = xbase + rr * XPITCH + half * 16;
#pragma unroll
                for (int dq = 0; dq < 3; ++dq)
#pragma unroll
                    for (int qb = 0; qb < 2; ++qb)
                        b[dq][qb] = *(const bf16x8*)(rbase + (qb * 32 + m + dq) * 32);
            }

            if (ri < 3) {
#pragma unroll
                for (int dq = 0; dq < 3; ++dq)
#pragma unroll
                    for (int kb = 0; kb < 2; ++kb)
                        a_cur[dq][kb] = wc[((ri * 3 + dq) * 4 + kb) * 64];  // global L2 hit
            }

            if (rok) {
                if (ri >= 1) {
#pragma unroll
                    for (int dq = 0; dq < 3; ++dq)
#pragma unroll
                        for (int kb = 0; kb < 2; ++kb)
#pragma unroll
                            for (int qb = 0; qb < 2; ++qb)
                                acc[1][kb][qb] = __builtin_amdgcn_mfma_f32_32x32x16_bf16(
                                    a_prev[dq][kb], b[dq][qb], acc[1][kb][qb], 0, 0, 0);
                }
                if (ri < 3) {
#pragma unroll
                    for (int dq = 0; dq < 3; ++dq)
#pragma unroll
                        for (int kb = 0; kb < 2; ++kb)
#pragma unroll
                            for (int qb = 0; qb < 2; ++qb)
                                acc[0][kb][qb] = __builtin_amdgcn_mfma_f32_32x32x16_bf16(
                                    a_cur[dq][kb], b[dq][qb], acc[0][kb][qb], 0, 0, 0);
                }
            }

            if (ri < 3) {
#pragma unroll
                for (int dq = 0; dq < 3; ++dq)
#pragma unroll
                    for (int kb = 0; kb < 2; ++kb) a_prev[dq][kb] = a_cur[dq][kb];
            }
        }
    };

    stage_x(0, 0);
    __syncthreads();  // prologue; pad-zero writes also covered

    for (int cc = 0; cc < 7; ++cc) {
        stage_x(cc + 1, (cc + 1) & 1);  // issue BEFORE compute -> overlap
        compute(cc & 1, cc);
        __syncthreads();                // drains only the 3 x-loads/thread
    }

    // ---- epilogue helpers (same verified mapping as round 3) ----
    auto tile_addr = [&](int it, int j) -> size_t {
        int oi = it >> 2, kbi = (it >> 1) & 1, qb = it & 1;
        int prow = p0 + pb * 2 + oi;
        int k = (kbs * 2 + kbi) * 32 + (lane >> 3) + j * 8;
        int q = qb * 32 + (lane & 7) * 4;
        return (((size_t)n * KK + k) * PP + prow) * QQ + q;
    };

    float* scr = (float*)scr_lds[w];  // private per wave, no cross-wave hazard

    auto process = [&](int it, f32x4 (&pv)[4]) {
        int oi = it >> 2, kbi = (it >> 1) & 1, qb = it & 1;
        f32x16 v = acc[oi][kbi][qb];
#pragma unroll
        for (int r = 0; r < 16; ++r) {
            int kl = (r & 3) + 8 * (r >> 2) + 4 * half;
            scr[kl * 32 + ((((m >> 2) ^ (kl & 7)) << 2) | (m & 3))] = v[r];
        }
        // same-wave LDS RAW: compiler inserts lgkmcnt wait
#pragma unroll
        for (int j = 0; j < 4; ++j) {
            int kl = (lane >> 3) + j * 8;
            f32x4 d = *(const f32x4*)(scr + kl * 32 + (((lane & 7) ^ (kl & 7)) << 2));
            f32x4 s = d + pv[j];
            __builtin_nontemporal_store(s, (f32x4*)(out + tile_addr(it, j)));
        }
    };

    // ---- peeled cc=7 with depth-1 per prefetch (32 VGPR, no spill) ----
    f32x4 pv0[4], pv1[4];
#pragma unroll
    for (int j = 0; j < 4; ++j) pv0[j] = *(const f32x4*)(per + tile_addr(0, j));

    compute(1, 7);  // reads xlds[1] only; A-frags direct from global

#pragma unroll
    for (int itp = 0; itp < 4; ++itp) {
        const int itA = itp * 2, itB = itp * 2 + 1;
#pragma unroll
        for (int j = 0; j < 4; ++j) pv1[j] = *(const f32x4*)(per + tile_addr(itB, j));
        process(itA, pv0);
        if (itp < 3) {
#pragma unroll
            for (int j = 0; j < 4; ++j)
                pv0[j] = *(const f32x4*)(per + tile_addr(itA + 2, j));
        }
        process(itB, pv1);
    }
}

extern "C" void kernel_launch(void* const* d_in, const int* in_sizes, int n_in,
                              void* d_out, int out_size, void* d_ws, size_t ws_size,
                              hipStream_t stream) {
    const float* x   = (const float*)d_in[0];  // [32][128][64][64]
    const float* W   = (const float*)d_in[1];  // [128][1152]
    const float* per = (const float*)d_in[2];  // [32][128][64][64]
    float* out = (float*)d_out;

    __bf16* xT = (__bf16*)d_ws;
    __bf16* Wf = (__bf16*)((char*)d_ws + XT_ELEMS * 2);

    prep_x<<<dim3(PP, NN), 256, 0, stream>>>(x, xT);
    prep_w<<<dim3(72), 256, 0, stream>>>(W, Wf);
    conv_main<<<dim3(PP / 4, NN), 256, 0, stream>>>(xT, Wf, per, out);
}